// Round 5
// baseline (1677.258 us; speedup 1.0000x reference)
//
#include <hip/hip_runtime.h>

#define N_NODES 100000
#define N_EDGES 1600000
#define IN_SIZE 512
#define HID_SIZE 256
#define OUT_SIZE 40
#define K_STEPS 10
#define ALPHA 0.1f

#define SCAN_B 2048   // 256 threads * 8 elems
#define SCAN_NB ((N_NODES + SCAN_B - 1) / SCAN_B)   // 49

#define HIST_B 64
#define HIST_R 1568   // 64 * 1568 = 100352 >= N_NODES

typedef _Float16 half8 __attribute__((ext_vector_type(8)));
typedef float f32x4 __attribute__((ext_vector_type(4)));

// ---------------- degrees: dst-range-partitioned LDS histogram ----------------
// 64 blocks x 1024 threads. Block b owns nodes [b*1568, (b+1)*1568).
// Streams the whole edge list coalesced; LDS atomics only for in-range ids;
// contiguous output writes (no device atomics, no 64B-line write amplification).
__global__ __launch_bounds__(1024) void degrees_part(const int* __restrict__ src,
                                                     const int* __restrict__ dst,
                                                     int* __restrict__ dego,
                                                     int* __restrict__ degi) {
    __shared__ int hout[HIST_R];
    __shared__ int hin[HIST_R];
    const int t = threadIdx.x;
    const int base = blockIdx.x * HIST_R;
    for (int j = t; j < HIST_R; j += 1024) { hout[j] = 0; hin[j] = 0; }
    __syncthreads();
    for (int i = t; i < N_EDGES; i += 1024) {
        const int s = src[i];
        const int d = dst[i];
        const unsigned us = (unsigned)(s - base);
        if (us < HIST_R) atomicAdd(&hout[us], 1);
        const unsigned ud = (unsigned)(d - base);
        if (ud < HIST_R) atomicAdd(&hin[ud], 1);
    }
    __syncthreads();
    for (int j = t; j < HIST_R; j += 1024) {
        const int node = base + j;
        if (node < N_NODES) { dego[node] = hout[j]; degi[node] = hin[j]; }
    }
}

// ---------------- norms ----------------
__global__ __launch_bounds__(256) void norms_kern(const int* __restrict__ dego,
                                                  const int* __restrict__ degi,
                                                  float* __restrict__ nsrc,
                                                  float* __restrict__ ndst) {
    int i = blockIdx.x * 256 + threadIdx.x;
    if (i < N_NODES) {
        nsrc[i] = 1.0f / sqrtf((float)max(dego[i], 1));
        ndst[i] = 1.0f / sqrtf((float)max(degi[i], 1));
    }
}

// ---------------- scan (exclusive prefix over deg_in -> row_ptr) ----------------
__global__ __launch_bounds__(256) void scan_block_sums(const int* __restrict__ deg,
                                                       int* __restrict__ bsum) {
    __shared__ int s[256];
    int t = threadIdx.x, b = blockIdx.x;
    int base = b * SCAN_B + t * 8;
    int v = 0;
#pragma unroll
    for (int u = 0; u < 8; ++u) { int i = base + u; if (i < N_NODES) v += deg[i]; }
    s[t] = v; __syncthreads();
    for (int off = 128; off > 0; off >>= 1) {
        if (t < off) s[t] += s[t + off];
        __syncthreads();
    }
    if (t == 0) bsum[b] = s[0];
}

__global__ void scan_offsets(const int* __restrict__ bsum, int* __restrict__ boff) {
    if (threadIdx.x == 0 && blockIdx.x == 0) {
        int run = 0;
        for (int b = 0; b < SCAN_NB; ++b) { boff[b] = run; run += bsum[b]; }
    }
}

__global__ __launch_bounds__(256) void scan_write(const int* __restrict__ deg,
                                                  const int* __restrict__ boff,
                                                  int* __restrict__ row_ptr) {
    __shared__ int s[256];
    int t = threadIdx.x, b = blockIdx.x;
    int base = b * SCAN_B + t * 8;
    int loc[8]; int tot = 0;
#pragma unroll
    for (int u = 0; u < 8; ++u) {
        int i = base + u;
        loc[u] = (i < N_NODES) ? deg[i] : 0;
        tot += loc[u];
    }
    s[t] = tot; __syncthreads();
    for (int off = 1; off < 256; off <<= 1) {
        int v = (t >= off) ? s[t - off] : 0;
        __syncthreads();
        s[t] += v;
        __syncthreads();
    }
    int run = boff[b] + s[t] - tot;
#pragma unroll
    for (int u = 0; u < 8; ++u) {
        int i = base + u;
        if (i < N_NODES) {
            row_ptr[i] = run;
            run += loc[u];
            if (i == N_NODES - 1) row_ptr[N_NODES] = run;
        }
    }
}

// ---------------- CSR fill: dst-range-partitioned, LDS cursor ----------------
// Block b owns the same node range; csr writes land in the block's contiguous
// rowp window (~100KB) -> lines fully populated in L2, writeback ~= payload.
__global__ __launch_bounds__(1024) void fill_part(const int* __restrict__ src,
                                                  const int* __restrict__ dst,
                                                  const int* __restrict__ rowp,
                                                  int* __restrict__ csr) {
    __shared__ int cur[HIST_R];
    const int t = threadIdx.x;
    const int base = blockIdx.x * HIST_R;
    for (int j = t; j < HIST_R; j += 1024) {
        const int node = base + j;
        cur[j] = (node < N_NODES) ? rowp[node] : 0;
    }
    __syncthreads();
    for (int i = t; i < N_EDGES; i += 1024) {
        const int d = dst[i];
        const unsigned ud = (unsigned)(d - base);
        if (ud < HIST_R) {
            const int pos = atomicAdd(&cur[ud], 1);
            csr[pos] = src[i];
        }
    }
}

// ---------------- prep: W1^T as fp16 [256][512] ----------------
__global__ __launch_bounds__(256) void prep_w1t(const float* __restrict__ W1,
                                                unsigned short* __restrict__ w1t) {
    int idx = blockIdx.x * 256 + threadIdx.x;   // 131072
    if (idx < IN_SIZE * HID_SIZE) {
        int n = idx >> 9;       // 0..255
        int k = idx & 511;      // 0..511
        _Float16 h = (_Float16)W1[(size_t)k * HID_SIZE + n];
        w1t[idx] = *(unsigned short*)&h;
    }
}

// ---------------- GEMM1: h1 = relu(X @ W1 + b1) in fp16 via MFMA ----------------
__global__ __launch_bounds__(512) void gemm1_f16(const float* __restrict__ X,
                                                 const unsigned short* __restrict__ w1t,
                                                 const float* __restrict__ b1,
                                                 _Float16* __restrict__ h1) {
    __shared__ __align__(16) _Float16 sA[128 * 64];
    __shared__ __align__(16) _Float16 sB[256 * 64];

    const int t    = threadIdx.x;
    const int lane = t & 63;
    const int w    = t >> 6;        // 0..7
    const int wr   = w >> 2;        // 0..1 : M
    const int wc   = w & 3;         // 0..3 : N
    const int n0   = blockIdx.x * 128;

    f32x4 acc[4][4];
#pragma unroll
    for (int i = 0; i < 4; ++i)
#pragma unroll
        for (int j = 0; j < 4; ++j) acc[i][j] = (f32x4)0.f;

    const int lo = lane & 15;
    const int hi = lane >> 4;
    const int l7 = lane & 7;

    for (int kk = 0; kk < IN_SIZE; kk += 64) {
        __syncthreads();
        // ---- stage A: X[128 rows][kk..kk+63] -> fp16, swizzled ----
#pragma unroll
        for (int i = 0; i < 2; ++i) {
            int id  = t + i * 512;          // 0..1023
            int row = id >> 3;              // 0..127
            int ch  = id & 7;               // 16B chunk (8 halves)
            int gr  = n0 + row;
            float4 x0 = make_float4(0.f, 0.f, 0.f, 0.f), x1 = x0;
            if (gr < N_NODES) {
                const float* p = X + (size_t)gr * IN_SIZE + kk + ch * 8;
                x0 = ((const float4*)p)[0];
                x1 = ((const float4*)p)[1];
            }
            half8 hv;
            hv[0] = (_Float16)x0.x; hv[1] = (_Float16)x0.y;
            hv[2] = (_Float16)x0.z; hv[3] = (_Float16)x0.w;
            hv[4] = (_Float16)x1.x; hv[5] = (_Float16)x1.y;
            hv[6] = (_Float16)x1.z; hv[7] = (_Float16)x1.w;
            *(half8*)&sA[row * 64 + ((ch ^ (row & 7)) << 3)] = hv;
        }
        // ---- stage B: W1^T[256 n][kk..kk+63] fp16, swizzled ----
#pragma unroll
        for (int i = 0; i < 4; ++i) {
            int id = t + i * 512;           // 0..2047
            int n  = id >> 3;               // 0..255
            int ch = id & 7;
            uint4 v = *(const uint4*)(w1t + (size_t)n * IN_SIZE + kk + ch * 8);
            *(uint4*)&sB[n * 64 + ((ch ^ (n & 7)) << 3)] = v;
        }
        __syncthreads();
        // ---- compute: 2 k-slices of 32 ----
#pragma unroll
        for (int s = 0; s < 2; ++s) {
            const int chs = ((s * 4 + hi) ^ l7) << 3;
            half8 af[4], bf[4];
#pragma unroll
            for (int f = 0; f < 4; ++f)
                af[f] = *(const half8*)&sA[(wr * 64 + f * 16 + lo) * 64 + chs];
#pragma unroll
            for (int f = 0; f < 4; ++f)
                bf[f] = *(const half8*)&sB[(wc * 64 + f * 16 + lo) * 64 + chs];
#pragma unroll
            for (int fi = 0; fi < 4; ++fi)
#pragma unroll
                for (int fj = 0; fj < 4; ++fj)
                    acc[fi][fj] = __builtin_amdgcn_mfma_f32_16x16x32_f16(
                        af[fi], bf[fj], acc[fi][fj], 0, 0, 0);
        }
    }

    // ---- epilogue: +b1, relu, fp16 store ----
    float b1v[4];
#pragma unroll
    for (int fj = 0; fj < 4; ++fj) b1v[fj] = b1[wc * 64 + fj * 16 + lo];
#pragma unroll
    for (int fi = 0; fi < 4; ++fi) {
#pragma unroll
        for (int fj = 0; fj < 4; ++fj) {
            const int col = wc * 64 + fj * 16 + lo;
#pragma unroll
            for (int r = 0; r < 4; ++r) {
                int grow = n0 + wr * 64 + fi * 16 + hi * 4 + r;
                if (grow < N_NODES) {
                    float v = acc[fi][fj][r] + b1v[fj];
                    v = fmaxf(v, 0.f);
                    h1[(size_t)grow * HID_SIZE + col] = (_Float16)v;
                }
            }
        }
    }
}

// ---------------- GEMM2: h0 = h1 @ W2 + b2 (fp32 accumulate) ----------------
__global__ __launch_bounds__(256) void gemm2(const _Float16* __restrict__ h1,
                                             const float* __restrict__ W2,
                                             const float* __restrict__ b2,
                                             float* __restrict__ h0) {
    __shared__ __align__(16) float sW2t[40 * 260];
    __shared__ __align__(16) unsigned short sH[64 * 264];

    const int t  = threadIdx.x;
    const int n0 = blockIdx.x * 64;

    for (int idx = t; idx < HID_SIZE * OUT_SIZE; idx += 256) {
        int c = idx / OUT_SIZE;
        int o = idx - c * OUT_SIZE;
        sW2t[o * 260 + c] = W2[idx];
    }
#pragma unroll
    for (int i = 0; i < 8; ++i) {
        int id  = t + i * 256;          // 0..2047
        int row = id >> 5;              // 0..63
        int ch  = id & 31;              // 16B chunks of 8 halves
        uint4 v = make_uint4(0, 0, 0, 0);
        if (n0 + row < N_NODES)
            v = *(const uint4*)(h1 + (size_t)(n0 + row) * HID_SIZE + ch * 8);
        *(uint4*)&sH[row * 264 + ch * 8] = v;
    }
    __syncthreads();

    const int r2 = t >> 2;
    const int q  = t & 3;
    const int o0 = q * 10;
    float acc2[10];
#pragma unroll
    for (int m = 0; m < 10; ++m) acc2[m] = b2[o0 + m];

    for (int c = 0; c < HID_SIZE; c += 8) {
        uint4 hv = *(const uint4*)&sH[r2 * 264 + c];
        const _Float16* hp = (const _Float16*)&hv;
        float f[8];
#pragma unroll
        for (int j = 0; j < 8; ++j) f[j] = (float)hp[j];
#pragma unroll
        for (int m = 0; m < 10; ++m) {
            const float4 w0 = *(const float4*)&sW2t[(o0 + m) * 260 + c];
            const float4 w1 = *(const float4*)&sW2t[(o0 + m) * 260 + c + 4];
            acc2[m] += f[0] * w0.x + f[1] * w0.y + f[2] * w0.z + f[3] * w0.w
                     + f[4] * w1.x + f[5] * w1.y + f[6] * w1.z + f[7] * w1.w;
        }
    }
    if (n0 + r2 < N_NODES) {
        float* dstp = h0 + (size_t)(n0 + r2) * OUT_SIZE + o0;
#pragma unroll
        for (int m = 0; m < 10; ++m) dstp[m] = acc2[m];
    }
}

// ---------------- g0 = nsrc * h0, fp16, rows padded to 64 halves (128B) ------
__global__ __launch_bounds__(320) void g0_init(const float* __restrict__ h0,
                                               const float* __restrict__ nsrc,
                                               _Float16* __restrict__ g) {
    const int tid = threadIdx.x;
    const int ln  = tid / 5;
    const int q   = tid - ln * 5;
    const int n   = blockIdx.x * 64 + ln;
    if (n >= N_NODES) return;
    const float ns = nsrc[n];
    const f32x4 a = *(const f32x4*)(h0 + (size_t)n * OUT_SIZE + q * 8);
    const f32x4 b = *(const f32x4*)(h0 + (size_t)n * OUT_SIZE + q * 8 + 4);
    half8 gv;
    gv[0] = (_Float16)(ns * a[0]); gv[1] = (_Float16)(ns * a[1]);
    gv[2] = (_Float16)(ns * a[2]); gv[3] = (_Float16)(ns * a[3]);
    gv[4] = (_Float16)(ns * b[0]); gv[5] = (_Float16)(ns * b[1]);
    gv[6] = (_Float16)(ns * b[2]); gv[7] = (_Float16)(ns * b[3]);
    *(half8*)(g + (size_t)n * 64 + q * 8) = gv;
}

// ---------------- APPNP step v3: scaled fp16 state, unweighted gather --------
__global__ __launch_bounds__(320) void appnp_step3(const _Float16* __restrict__ gin,
                                                   const float* __restrict__ h0,
                                                   const int* __restrict__ rowp,
                                                   const int* __restrict__ csr,
                                                   const float* __restrict__ nsrc,
                                                   const float* __restrict__ ndst,
                                                   _Float16* __restrict__ gout,
                                                   float* __restrict__ hout,
                                                   int last) {
    const int tid = threadIdx.x;
    const int ln  = tid / 5;
    const int q   = tid - ln * 5;
    const int n   = blockIdx.x * 64 + ln;
    if (n >= N_NODES) return;

    const int beg = rowp[n];
    const int end = rowp[n + 1];
    const _Float16* gq = gin + q * 8;

    float acc[8];
#pragma unroll
    for (int j = 0; j < 8; ++j) acc[j] = 0.f;

    int e = beg;
    for (; e + 4 <= end; e += 4) {
        const int s0 = csr[e + 0];
        const int s1 = csr[e + 1];
        const int s2 = csr[e + 2];
        const int s3 = csr[e + 3];
        const half8 v0 = *(const half8*)(gq + (size_t)s0 * 64);
        const half8 v1 = *(const half8*)(gq + (size_t)s1 * 64);
        const half8 v2 = *(const half8*)(gq + (size_t)s2 * 64);
        const half8 v3 = *(const half8*)(gq + (size_t)s3 * 64);
#pragma unroll
        for (int j = 0; j < 8; ++j)
            acc[j] += (float)v0[j] + (float)v1[j] + (float)v2[j] + (float)v3[j];
    }
    for (; e < end; ++e) {
        const int s0 = csr[e];
        const half8 v0 = *(const half8*)(gq + (size_t)s0 * 64);
#pragma unroll
        for (int j = 0; j < 8; ++j) acc[j] += (float)v0[j];
    }

    const float nd = (1.0f - ALPHA) * ndst[n];
    const f32x4 h0a = *(const f32x4*)(h0 + (size_t)n * OUT_SIZE + q * 8);
    const f32x4 h0b = *(const f32x4*)(h0 + (size_t)n * OUT_SIZE + q * 8 + 4);
    float r[8];
    r[0] = nd * acc[0] + ALPHA * h0a[0]; r[1] = nd * acc[1] + ALPHA * h0a[1];
    r[2] = nd * acc[2] + ALPHA * h0a[2]; r[3] = nd * acc[3] + ALPHA * h0a[3];
    r[4] = nd * acc[4] + ALPHA * h0b[0]; r[5] = nd * acc[5] + ALPHA * h0b[1];
    r[6] = nd * acc[6] + ALPHA * h0b[2]; r[7] = nd * acc[7] + ALPHA * h0b[3];

    if (last) {
        f32x4 ra, rb;
        ra[0] = r[0]; ra[1] = r[1]; ra[2] = r[2]; ra[3] = r[3];
        rb[0] = r[4]; rb[1] = r[5]; rb[2] = r[6]; rb[3] = r[7];
        *(f32x4*)(hout + (size_t)n * OUT_SIZE + q * 8) = ra;
        *(f32x4*)(hout + (size_t)n * OUT_SIZE + q * 8 + 4) = rb;
    } else {
        const float ns = nsrc[n];
        half8 gv;
#pragma unroll
        for (int j = 0; j < 8; ++j) gv[j] = (_Float16)(ns * r[j]);
        *(half8*)(gout + (size_t)n * 64 + q * 8) = gv;
    }
}

// ---------------- launcher ----------------
extern "C" void kernel_launch(void* const* d_in, const int* in_sizes, int n_in,
                              void* d_out, int out_size, void* d_ws, size_t ws_size,
                              hipStream_t stream) {
    const float* X   = (const float*)d_in[0];
    const int*   src = (const int*)d_in[1];
    const int*   dst = (const int*)d_in[2];
    const float* W1  = (const float*)d_in[3];
    const float* b1  = (const float*)d_in[4];
    const float* W2  = (const float*)d_in[5];
    const float* b2  = (const float*)d_in[6];
    float* out = (float*)d_out;

    char* ws = (char*)d_ws;
    size_t off = 0;
    auto alloc = [&](size_t bytes) -> void* {
        void* p = ws + off;
        off = (off + bytes + 255) & ~(size_t)255;
        return p;
    };
    // persistent
    float* h0 = (float*)alloc((size_t)N_NODES * OUT_SIZE * 4);     // 16 MB
    const size_t mark = off;

    // ---- phase A (MLP) region ----
    unsigned short* w1t = (unsigned short*)alloc((size_t)IN_SIZE * HID_SIZE * 2);  // 256 KB
    _Float16*       h1  = (_Float16*)alloc((size_t)N_NODES * HID_SIZE * 2);        // 51.2 MB

    // ---- phase B region: ALIASES phase A (w1t/h1 dead after gemm2) ----
    off = mark;
    _Float16* gA = (_Float16*)alloc((size_t)N_NODES * 64 * 2);   // 12.8 MB
    _Float16* gB = (_Float16*)alloc((size_t)N_NODES * 64 * 2);   // 12.8 MB
    float* nsrc = (float*)alloc((size_t)N_NODES * 4);
    float* ndst = (float*)alloc((size_t)N_NODES * 4);
    int* dego   = (int*)alloc((size_t)N_NODES * 4);
    int* degi   = (int*)alloc((size_t)N_NODES * 4);
    int* rowp   = (int*)alloc((size_t)(N_NODES + 1) * 4);
    int* csr    = (int*)alloc((size_t)N_EDGES * 4);              // 6.4 MB
    int* bsum   = (int*)alloc((size_t)SCAN_NB * 4);
    int* boff   = (int*)alloc((size_t)SCAN_NB * 4);

    const int ngrid = (N_NODES + 255) / 256;           // 391
    const int pgrid = (N_NODES + 63) / 64;             // 1563 (320-thread blocks)

    // ---- phase A: MLP first (its scratch is aliased by phase B buffers) ----
    prep_w1t<<<(IN_SIZE * HID_SIZE + 255) / 256, 256, 0, stream>>>(W1, w1t);
    gemm1_f16<<<(N_NODES + 127) / 128, 512, 0, stream>>>(X, w1t, b1, h1);
    gemm2<<<(N_NODES + 63) / 64, 256, 0, stream>>>(h1, W2, b2, h0);

    // ---- phase B: CSR build (after gemm2 -> h1/w1t dead, aliasing safe) ----
    degrees_part<<<HIST_B, 1024, 0, stream>>>(src, dst, dego, degi);
    norms_kern<<<ngrid, 256, 0, stream>>>(dego, degi, nsrc, ndst);
    scan_block_sums<<<SCAN_NB, 256, 0, stream>>>(degi, bsum);
    scan_offsets<<<1, 64, 0, stream>>>(bsum, boff);
    scan_write<<<SCAN_NB, 256, 0, stream>>>(degi, boff, rowp);
    fill_part<<<HIST_B, 1024, 0, stream>>>(src, dst, rowp, csr);

    // ---- scaled initial state ----
    g0_init<<<pgrid, 320, 0, stream>>>(h0, nsrc, gA);

    // ---- propagation ----
    const _Float16* gin = gA;
    for (int s = 0; s < K_STEPS; ++s) {
        const int last = (s == K_STEPS - 1) ? 1 : 0;
        _Float16* gout = (s & 1) ? gA : gB;
        appnp_step3<<<pgrid, 320, 0, stream>>>(gin, h0, rowp, csr, nsrc, ndst,
                                               gout, out, last);
        gin = gout;
    }
}

// Round 6
// 550.165 us; speedup vs baseline: 3.0486x; 3.0486x over previous
//
#include <hip/hip_runtime.h>

#define N_NODES 100000
#define N_EDGES 1600000
#define IN_SIZE 512
#define HID_SIZE 256
#define OUT_SIZE 40
#define K_STEPS 10
#define ALPHA 0.1f

// radix-by-dst build
#define NCH 250            // chunks; 250 * 6400 = 1.6M
#define CH_E 6400          // edges per chunk (int4-aligned)
#define NBUK 391           // buckets of 256 nodes; 391*256 = 100096 >= N
// deg_out partial histograms
#define NRS 8              // src ranges
#define HRS 12544          // 8 * 12544 = 100352 >= N
#define NCS 16             // src chunks; 16 * 100000 = 1.6M
#define CS_E 100000

typedef _Float16 half8 __attribute__((ext_vector_type(8)));
typedef float f32x4 __attribute__((ext_vector_type(4)));

struct __align__(8) Entry { int s; int d; };

// ---------------- pass 1: per-chunk bucket histogram of dst ----------------
__global__ __launch_bounds__(512) void hist_pass(const int* __restrict__ dst,
                                                 int* __restrict__ cnt) {
    __shared__ int h[NBUK];
    const int t = threadIdx.x, c = blockIdx.x;
    for (int j = t; j < NBUK; j += 512) h[j] = 0;
    __syncthreads();
    const int4* d4 = (const int4*)(dst + c * CH_E);
    for (int i = t; i < CH_E / 4; i += 512) {
        const int4 v = d4[i];
        atomicAdd(&h[v.x >> 8], 1);
        atomicAdd(&h[v.y >> 8], 1);
        atomicAdd(&h[v.z >> 8], 1);
        atomicAdd(&h[v.w >> 8], 1);
    }
    __syncthreads();
    for (int j = t; j < NBUK; j += 512) cnt[c * NBUK + j] = h[j];
}

// ---------------- pass 2: bucket offsets (single block) ----------------
// boff[b] = global start of bucket b; off[c][b] = start for chunk c in bucket b.
__global__ __launch_bounds__(512) void bucket_scan(const int* __restrict__ cnt,
                                                   int* __restrict__ off,
                                                   int* __restrict__ boff) {
    __shared__ int tot[512];
    const int b = threadIdx.x;
    int s = 0;
    if (b < NBUK)
        for (int c = 0; c < NCH; ++c) s += cnt[c * NBUK + b];
    tot[b] = s;
    __syncthreads();
    for (int o = 1; o < 512; o <<= 1) {
        const int v = (b >= o) ? tot[b - o] : 0;
        __syncthreads();
        tot[b] += v;
        __syncthreads();
    }
    if (b < NBUK) {
        int run = tot[b] - s;           // exclusive prefix
        boff[b] = run;
        for (int c = 0; c < NCH; ++c) { off[c * NBUK + b] = run; run += cnt[c * NBUK + b]; }
        if (b == NBUK - 1) boff[NBUK] = tot[b];
    }
}

// ---------------- pass 3: scatter edges into bucket-grouped ebuf ----------------
__global__ __launch_bounds__(512) void scatter_pass(const int* __restrict__ src,
                                                    const int* __restrict__ dst,
                                                    const int* __restrict__ off,
                                                    Entry* __restrict__ ebuf) {
    __shared__ int cur[NBUK];
    const int t = threadIdx.x, c = blockIdx.x;
    for (int j = t; j < NBUK; j += 512) cur[j] = off[c * NBUK + j];
    __syncthreads();
    const int4* s4 = (const int4*)(src + c * CH_E);
    const int4* d4 = (const int4*)(dst + c * CH_E);
    for (int i = t; i < CH_E / 4; i += 512) {
        const int4 sv = s4[i];
        const int4 dv = d4[i];
        Entry e;
        int p;
        p = atomicAdd(&cur[dv.x >> 8], 1); e.s = sv.x; e.d = dv.x; ebuf[p] = e;
        p = atomicAdd(&cur[dv.y >> 8], 1); e.s = sv.y; e.d = dv.y; ebuf[p] = e;
        p = atomicAdd(&cur[dv.z >> 8], 1); e.s = sv.z; e.d = dv.z; ebuf[p] = e;
        p = atomicAdd(&cur[dv.w >> 8], 1); e.s = sv.w; e.d = dv.w; ebuf[p] = e;
    }
}

// ---------------- pass 4: per-bucket CSR fill + rowp + ndst ----------------
// Bucket b owns nodes [b*256, b*256+256) and csr window [boff[b], boff[b+1]).
__global__ __launch_bounds__(256) void bucket_csr(const Entry* __restrict__ ebuf,
                                                  const int* __restrict__ boff,
                                                  int* __restrict__ rowp,
                                                  float* __restrict__ ndst,
                                                  int* __restrict__ csr) {
    __shared__ int hist[256];
    __shared__ int pref[256];
    __shared__ int cur[256];
    const int t = threadIdx.x, b = blockIdx.x;
    const int beg = boff[b], end = boff[b + 1];
    hist[t] = 0;
    __syncthreads();
    for (int i = beg + t; i < end; i += 256)
        atomicAdd(&hist[ebuf[i].d & 255], 1);
    __syncthreads();
    const int h = hist[t];
    pref[t] = h;
    __syncthreads();
    for (int o = 1; o < 256; o <<= 1) {
        const int v = (t >= o) ? pref[t - o] : 0;
        __syncthreads();
        pref[t] += v;
        __syncthreads();
    }
    const int val = beg + pref[t] - h;   // exclusive prefix + bucket base
    const int n = (b << 8) + t;
    if (n <= N_NODES) rowp[n] = val;     // n==N_NODES lands on total E
    if (n < N_NODES) ndst[n] = 1.0f / sqrtf((float)max(h, 1));
    cur[t] = val;
    __syncthreads();
    for (int i = beg + t; i < end; i += 256) {
        const Entry e = ebuf[i];
        const int pos = atomicAdd(&cur[e.d & 255], 1);
        csr[pos] = e.s;
    }
}

// ---------------- deg_out: range x chunk partial histograms (non-atomic out) --
__global__ __launch_bounds__(512) void degsrc_part(const int* __restrict__ src,
                                                   int* __restrict__ partial) {
    __shared__ int h[HRS];
    const int t = threadIdx.x;
    const int r = blockIdx.x & (NRS - 1);
    const int c = blockIdx.x >> 3;
    const int base = r * HRS;
    for (int j = t; j < HRS; j += 512) h[j] = 0;
    __syncthreads();
    const int4* s4 = (const int4*)(src + (size_t)c * CS_E);
    for (int i = t; i < CS_E / 4; i += 512) {
        const int4 v = s4[i];
        unsigned u;
        u = (unsigned)(v.x - base); if (u < HRS) atomicAdd(&h[u], 1);
        u = (unsigned)(v.y - base); if (u < HRS) atomicAdd(&h[u], 1);
        u = (unsigned)(v.z - base); if (u < HRS) atomicAdd(&h[u], 1);
        u = (unsigned)(v.w - base); if (u < HRS) atomicAdd(&h[u], 1);
    }
    __syncthreads();
    for (int j = t; j < HRS; j += 512) partial[(size_t)c * (NRS * HRS) + base + j] = h[j];
}

__global__ __launch_bounds__(256) void nsrc_reduce(const int* __restrict__ partial,
                                                   float* __restrict__ nsrc) {
    const int n = blockIdx.x * 256 + threadIdx.x;   // grid covers NRS*HRS
    int s = 0;
#pragma unroll
    for (int c = 0; c < NCS; ++c) s += partial[(size_t)c * (NRS * HRS) + n];
    if (n < N_NODES) nsrc[n] = 1.0f / sqrtf((float)max(s, 1));
}

// ---------------- prep: W1^T as fp16 [256][512] ----------------
__global__ __launch_bounds__(256) void prep_w1t(const float* __restrict__ W1,
                                                unsigned short* __restrict__ w1t) {
    int idx = blockIdx.x * 256 + threadIdx.x;
    if (idx < IN_SIZE * HID_SIZE) {
        int n = idx >> 9;
        int k = idx & 511;
        _Float16 h = (_Float16)W1[(size_t)k * HID_SIZE + n];
        w1t[idx] = *(unsigned short*)&h;
    }
}

// ---------------- GEMM1: h1 = relu(X @ W1 + b1) in fp16 via MFMA ----------------
__global__ __launch_bounds__(512) void gemm1_f16(const float* __restrict__ X,
                                                 const unsigned short* __restrict__ w1t,
                                                 const float* __restrict__ b1,
                                                 _Float16* __restrict__ h1) {
    __shared__ __align__(16) _Float16 sA[128 * 64];
    __shared__ __align__(16) _Float16 sB[256 * 64];

    const int t    = threadIdx.x;
    const int lane = t & 63;
    const int w    = t >> 6;
    const int wr   = w >> 2;
    const int wc   = w & 3;
    const int n0   = blockIdx.x * 128;

    f32x4 acc[4][4];
#pragma unroll
    for (int i = 0; i < 4; ++i)
#pragma unroll
        for (int j = 0; j < 4; ++j) acc[i][j] = (f32x4)0.f;

    const int lo = lane & 15;
    const int hi = lane >> 4;
    const int l7 = lane & 7;

    for (int kk = 0; kk < IN_SIZE; kk += 64) {
        __syncthreads();
#pragma unroll
        for (int i = 0; i < 2; ++i) {
            int id  = t + i * 512;
            int row = id >> 3;
            int ch  = id & 7;
            int gr  = n0 + row;
            float4 x0 = make_float4(0.f, 0.f, 0.f, 0.f), x1 = x0;
            if (gr < N_NODES) {
                const float* p = X + (size_t)gr * IN_SIZE + kk + ch * 8;
                x0 = ((const float4*)p)[0];
                x1 = ((const float4*)p)[1];
            }
            half8 hv;
            hv[0] = (_Float16)x0.x; hv[1] = (_Float16)x0.y;
            hv[2] = (_Float16)x0.z; hv[3] = (_Float16)x0.w;
            hv[4] = (_Float16)x1.x; hv[5] = (_Float16)x1.y;
            hv[6] = (_Float16)x1.z; hv[7] = (_Float16)x1.w;
            *(half8*)&sA[row * 64 + ((ch ^ (row & 7)) << 3)] = hv;
        }
#pragma unroll
        for (int i = 0; i < 4; ++i) {
            int id = t + i * 512;
            int n  = id >> 3;
            int ch = id & 7;
            uint4 v = *(const uint4*)(w1t + (size_t)n * IN_SIZE + kk + ch * 8);
            *(uint4*)&sB[n * 64 + ((ch ^ (n & 7)) << 3)] = v;
        }
        __syncthreads();
#pragma unroll
        for (int s = 0; s < 2; ++s) {
            const int chs = ((s * 4 + hi) ^ l7) << 3;
            half8 af[4], bf[4];
#pragma unroll
            for (int f = 0; f < 4; ++f)
                af[f] = *(const half8*)&sA[(wr * 64 + f * 16 + lo) * 64 + chs];
#pragma unroll
            for (int f = 0; f < 4; ++f)
                bf[f] = *(const half8*)&sB[(wc * 64 + f * 16 + lo) * 64 + chs];
#pragma unroll
            for (int fi = 0; fi < 4; ++fi)
#pragma unroll
                for (int fj = 0; fj < 4; ++fj)
                    acc[fi][fj] = __builtin_amdgcn_mfma_f32_16x16x32_f16(
                        af[fi], bf[fj], acc[fi][fj], 0, 0, 0);
        }
    }

    float b1v[4];
#pragma unroll
    for (int fj = 0; fj < 4; ++fj) b1v[fj] = b1[wc * 64 + fj * 16 + lo];
#pragma unroll
    for (int fi = 0; fi < 4; ++fi) {
#pragma unroll
        for (int fj = 0; fj < 4; ++fj) {
            const int col = wc * 64 + fj * 16 + lo;
#pragma unroll
            for (int r = 0; r < 4; ++r) {
                int grow = n0 + wr * 64 + fi * 16 + hi * 4 + r;
                if (grow < N_NODES) {
                    float v = acc[fi][fj][r] + b1v[fj];
                    v = fmaxf(v, 0.f);
                    h1[(size_t)grow * HID_SIZE + col] = (_Float16)v;
                }
            }
        }
    }
}

// ---------------- GEMM2: h0 = h1 @ W2 + b2 (fp32 accumulate) ----------------
__global__ __launch_bounds__(256) void gemm2(const _Float16* __restrict__ h1,
                                             const float* __restrict__ W2,
                                             const float* __restrict__ b2,
                                             float* __restrict__ h0) {
    __shared__ __align__(16) float sW2t[40 * 260];
    __shared__ __align__(16) unsigned short sH[64 * 264];

    const int t  = threadIdx.x;
    const int n0 = blockIdx.x * 64;

    for (int idx = t; idx < HID_SIZE * OUT_SIZE; idx += 256) {
        int c = idx / OUT_SIZE;
        int o = idx - c * OUT_SIZE;
        sW2t[o * 260 + c] = W2[idx];
    }
#pragma unroll
    for (int i = 0; i < 8; ++i) {
        int id  = t + i * 256;
        int row = id >> 5;
        int ch  = id & 31;
        uint4 v = make_uint4(0, 0, 0, 0);
        if (n0 + row < N_NODES)
            v = *(const uint4*)(h1 + (size_t)(n0 + row) * HID_SIZE + ch * 8);
        *(uint4*)&sH[row * 264 + ch * 8] = v;
    }
    __syncthreads();

    const int r2 = t >> 2;
    const int q  = t & 3;
    const int o0 = q * 10;
    float acc2[10];
#pragma unroll
    for (int m = 0; m < 10; ++m) acc2[m] = b2[o0 + m];

    for (int c = 0; c < HID_SIZE; c += 8) {
        uint4 hv = *(const uint4*)&sH[r2 * 264 + c];
        const _Float16* hp = (const _Float16*)&hv;
        float f[8];
#pragma unroll
        for (int j = 0; j < 8; ++j) f[j] = (float)hp[j];
#pragma unroll
        for (int m = 0; m < 10; ++m) {
            const float4 w0 = *(const float4*)&sW2t[(o0 + m) * 260 + c];
            const float4 w1 = *(const float4*)&sW2t[(o0 + m) * 260 + c + 4];
            acc2[m] += f[0] * w0.x + f[1] * w0.y + f[2] * w0.z + f[3] * w0.w
                     + f[4] * w1.x + f[5] * w1.y + f[6] * w1.z + f[7] * w1.w;
        }
    }
    if (n0 + r2 < N_NODES) {
        float* dstp = h0 + (size_t)(n0 + r2) * OUT_SIZE + o0;
#pragma unroll
        for (int m = 0; m < 10; ++m) dstp[m] = acc2[m];
    }
}

// ---------------- g0 = nsrc * h0, fp16, rows padded to 64 halves (128B) ------
__global__ __launch_bounds__(320) void g0_init(const float* __restrict__ h0,
                                               const float* __restrict__ nsrc,
                                               _Float16* __restrict__ g) {
    const int tid = threadIdx.x;
    const int ln  = tid / 5;
    const int q   = tid - ln * 5;
    const int n   = blockIdx.x * 64 + ln;
    if (n >= N_NODES) return;
    const float ns = nsrc[n];
    const f32x4 a = *(const f32x4*)(h0 + (size_t)n * OUT_SIZE + q * 8);
    const f32x4 b = *(const f32x4*)(h0 + (size_t)n * OUT_SIZE + q * 8 + 4);
    half8 gv;
    gv[0] = (_Float16)(ns * a[0]); gv[1] = (_Float16)(ns * a[1]);
    gv[2] = (_Float16)(ns * a[2]); gv[3] = (_Float16)(ns * a[3]);
    gv[4] = (_Float16)(ns * b[0]); gv[5] = (_Float16)(ns * b[1]);
    gv[6] = (_Float16)(ns * b[2]); gv[7] = (_Float16)(ns * b[3]);
    *(half8*)(g + (size_t)n * 64 + q * 8) = gv;
}

// ---------------- APPNP step: scaled fp16 state, unweighted gather ----------
__global__ __launch_bounds__(320) void appnp_step3(const _Float16* __restrict__ gin,
                                                   const float* __restrict__ h0,
                                                   const int* __restrict__ rowp,
                                                   const int* __restrict__ csr,
                                                   const float* __restrict__ nsrc,
                                                   const float* __restrict__ ndst,
                                                   _Float16* __restrict__ gout,
                                                   float* __restrict__ hout,
                                                   int last) {
    const int tid = threadIdx.x;
    const int ln  = tid / 5;
    const int q   = tid - ln * 5;
    const int n   = blockIdx.x * 64 + ln;
    if (n >= N_NODES) return;

    const int beg = rowp[n];
    const int end = rowp[n + 1];
    const _Float16* gq = gin + q * 8;

    float acc[8];
#pragma unroll
    for (int j = 0; j < 8; ++j) acc[j] = 0.f;

    int e = beg;
    for (; e + 4 <= end; e += 4) {
        const int s0 = csr[e + 0];
        const int s1 = csr[e + 1];
        const int s2 = csr[e + 2];
        const int s3 = csr[e + 3];
        const half8 v0 = *(const half8*)(gq + (size_t)s0 * 64);
        const half8 v1 = *(const half8*)(gq + (size_t)s1 * 64);
        const half8 v2 = *(const half8*)(gq + (size_t)s2 * 64);
        const half8 v3 = *(const half8*)(gq + (size_t)s3 * 64);
#pragma unroll
        for (int j = 0; j < 8; ++j)
            acc[j] += (float)v0[j] + (float)v1[j] + (float)v2[j] + (float)v3[j];
    }
    for (; e < end; ++e) {
        const int s0 = csr[e];
        const half8 v0 = *(const half8*)(gq + (size_t)s0 * 64);
#pragma unroll
        for (int j = 0; j < 8; ++j) acc[j] += (float)v0[j];
    }

    const float nd = (1.0f - ALPHA) * ndst[n];
    const f32x4 h0a = *(const f32x4*)(h0 + (size_t)n * OUT_SIZE + q * 8);
    const f32x4 h0b = *(const f32x4*)(h0 + (size_t)n * OUT_SIZE + q * 8 + 4);
    float r[8];
    r[0] = nd * acc[0] + ALPHA * h0a[0]; r[1] = nd * acc[1] + ALPHA * h0a[1];
    r[2] = nd * acc[2] + ALPHA * h0a[2]; r[3] = nd * acc[3] + ALPHA * h0a[3];
    r[4] = nd * acc[4] + ALPHA * h0b[0]; r[5] = nd * acc[5] + ALPHA * h0b[1];
    r[6] = nd * acc[6] + ALPHA * h0b[2]; r[7] = nd * acc[7] + ALPHA * h0b[3];

    if (last) {
        f32x4 ra, rb;
        ra[0] = r[0]; ra[1] = r[1]; ra[2] = r[2]; ra[3] = r[3];
        rb[0] = r[4]; rb[1] = r[5]; rb[2] = r[6]; rb[3] = r[7];
        *(f32x4*)(hout + (size_t)n * OUT_SIZE + q * 8) = ra;
        *(f32x4*)(hout + (size_t)n * OUT_SIZE + q * 8 + 4) = rb;
    } else {
        const float ns = nsrc[n];
        half8 gv;
#pragma unroll
        for (int j = 0; j < 8; ++j) gv[j] = (_Float16)(ns * r[j]);
        *(half8*)(gout + (size_t)n * 64 + q * 8) = gv;
    }
}

// ---------------- launcher ----------------
extern "C" void kernel_launch(void* const* d_in, const int* in_sizes, int n_in,
                              void* d_out, int out_size, void* d_ws, size_t ws_size,
                              hipStream_t stream) {
    const float* X   = (const float*)d_in[0];
    const int*   src = (const int*)d_in[1];
    const int*   dst = (const int*)d_in[2];
    const float* W1  = (const float*)d_in[3];
    const float* b1  = (const float*)d_in[4];
    const float* W2  = (const float*)d_in[5];
    const float* b2  = (const float*)d_in[6];
    float* out = (float*)d_out;

    char* ws = (char*)d_ws;
    size_t off = 0;
    auto alloc = [&](size_t bytes) -> void* {
        void* p = ws + off;
        off = (off + bytes + 255) & ~(size_t)255;
        return p;
    };
    // persistent
    float* h0 = (float*)alloc((size_t)N_NODES * OUT_SIZE * 4);     // 16 MB
    const size_t mark = off;

    // ---- phase A (MLP) region ----
    unsigned short* w1t = (unsigned short*)alloc((size_t)IN_SIZE * HID_SIZE * 2);  // 256 KB
    _Float16*       h1  = (_Float16*)alloc((size_t)N_NODES * HID_SIZE * 2);        // 51.2 MB

    // ---- phase B region: aliases phase A (w1t/h1 dead after gemm2) ----
    off = mark;
    _Float16* gA = (_Float16*)alloc((size_t)N_NODES * 64 * 2);   // 12.8 MB
    _Float16* gB = (_Float16*)alloc((size_t)N_NODES * 64 * 2);   // 12.8 MB
    // partial (6.5 MB) aliases gA: dead before g0_init writes gA
    int*   partial = (int*)gA;                                   // [NCS][NRS*HRS]
    // ebuf (12.8 MB) aliases gB: dead before step 0 writes gB
    Entry* ebuf    = (Entry*)gB;
    float* nsrc = (float*)alloc((size_t)N_NODES * 4);
    float* ndst = (float*)alloc((size_t)N_NODES * 4);
    int* rowp   = (int*)alloc((size_t)(N_NODES + 2) * 4);
    int* csr    = (int*)alloc((size_t)N_EDGES * 4);              // 6.4 MB
    int* cnt    = (int*)alloc((size_t)NCH * NBUK * 4);           // 391 KB
    int* offb   = (int*)alloc((size_t)NCH * NBUK * 4);           // 391 KB
    int* boff   = (int*)alloc((size_t)(NBUK + 1) * 4);

    const int pgrid = (N_NODES + 63) / 64;             // 1563 (320-thread blocks)

    // ---- phase A: MLP ----
    prep_w1t<<<(IN_SIZE * HID_SIZE + 255) / 256, 256, 0, stream>>>(W1, w1t);
    gemm1_f16<<<(N_NODES + 127) / 128, 512, 0, stream>>>(X, w1t, b1, h1);
    gemm2<<<(N_NODES + 63) / 64, 256, 0, stream>>>(h1, W2, b2, h0);

    // ---- phase B: radix CSR build (no device atomics anywhere) ----
    hist_pass<<<NCH, 512, 0, stream>>>(dst, cnt);
    bucket_scan<<<1, 512, 0, stream>>>(cnt, offb, boff);
    scatter_pass<<<NCH, 512, 0, stream>>>(src, dst, offb, ebuf);
    bucket_csr<<<NBUK, 256, 0, stream>>>(ebuf, boff, rowp, ndst, csr);

    // ---- deg_out -> nsrc (non-atomic partial histograms) ----
    degsrc_part<<<NRS * NCS, 512, 0, stream>>>(src, partial);
    nsrc_reduce<<<(NRS * HRS) / 256, 256, 0, stream>>>(partial, nsrc);

    // ---- scaled initial state (partial dead; gA now live) ----
    g0_init<<<pgrid, 320, 0, stream>>>(h0, nsrc, gA);

    // ---- propagation (ebuf dead; gB now live) ----
    const _Float16* gin = gA;
    for (int s = 0; s < K_STEPS; ++s) {
        const int last = (s == K_STEPS - 1) ? 1 : 0;
        _Float16* gout = (s & 1) ? gA : gB;
        appnp_step3<<<pgrid, 320, 0, stream>>>(gin, h0, rowp, csr, nsrc, ndst,
                                               gout, out, last);
        gin = gout;
    }
}

// Round 7
// 548.868 us; speedup vs baseline: 3.0559x; 1.0024x over previous
//
#include <hip/hip_runtime.h>

#define N_NODES 100000
#define N_EDGES 1600000
#define IN_SIZE 512
#define HID_SIZE 256
#define OUT_SIZE 40
#define K_STEPS 10
#define ALPHA 0.1f

// radix-by-dst build
#define NCH 250            // chunks; 250 * 6400 = 1.6M
#define CH_E 6400          // edges per chunk (int4-aligned)
#define NBUK 391           // buckets of 256 nodes; 391*256 = 100096 >= N
// deg_out partial histograms
#define NRS 8              // src ranges
#define HRS 12544          // 8 * 12544 = 100352 >= N
#define NCS 16             // src chunks; 16 * 100000 = 1.6M
#define CS_E 100000

typedef _Float16 half8 __attribute__((ext_vector_type(8)));
typedef float f32x4 __attribute__((ext_vector_type(4)));

struct __align__(8) Entry { int s; int d; };

// ---------------- pass 1: per-chunk bucket histogram of dst ----------------
__global__ __launch_bounds__(512) void hist_pass(const int* __restrict__ dst,
                                                 int* __restrict__ cnt) {
    __shared__ int h[NBUK];
    const int t = threadIdx.x, c = blockIdx.x;
    for (int j = t; j < NBUK; j += 512) h[j] = 0;
    __syncthreads();
    const int4* d4 = (const int4*)(dst + c * CH_E);
    for (int i = t; i < CH_E / 4; i += 512) {
        const int4 v = d4[i];
        atomicAdd(&h[v.x >> 8], 1);
        atomicAdd(&h[v.y >> 8], 1);
        atomicAdd(&h[v.z >> 8], 1);
        atomicAdd(&h[v.w >> 8], 1);
    }
    __syncthreads();
    for (int j = t; j < NBUK; j += 512) cnt[c * NBUK + j] = h[j];
}

// ---------------- pass 2: bucket offsets (single block) ----------------
__global__ __launch_bounds__(512) void bucket_scan(const int* __restrict__ cnt,
                                                   int* __restrict__ off,
                                                   int* __restrict__ boff) {
    __shared__ int tot[512];
    const int b = threadIdx.x;
    int s = 0;
    if (b < NBUK)
        for (int c = 0; c < NCH; ++c) s += cnt[c * NBUK + b];
    tot[b] = s;
    __syncthreads();
    for (int o = 1; o < 512; o <<= 1) {
        const int v = (b >= o) ? tot[b - o] : 0;
        __syncthreads();
        tot[b] += v;
        __syncthreads();
    }
    if (b < NBUK) {
        int run = tot[b] - s;           // exclusive prefix
        boff[b] = run;
        for (int c = 0; c < NCH; ++c) { off[c * NBUK + b] = run; run += cnt[c * NBUK + b]; }
        if (b == NBUK - 1) boff[NBUK] = tot[b];
    }
}

// ---------------- pass 3: scatter edges into bucket-grouped ebuf ----------------
__global__ __launch_bounds__(512) void scatter_pass(const int* __restrict__ src,
                                                    const int* __restrict__ dst,
                                                    const int* __restrict__ off,
                                                    Entry* __restrict__ ebuf) {
    __shared__ int cur[NBUK];
    const int t = threadIdx.x, c = blockIdx.x;
    for (int j = t; j < NBUK; j += 512) cur[j] = off[c * NBUK + j];
    __syncthreads();
    const int4* s4 = (const int4*)(src + c * CH_E);
    const int4* d4 = (const int4*)(dst + c * CH_E);
    for (int i = t; i < CH_E / 4; i += 512) {
        const int4 sv = s4[i];
        const int4 dv = d4[i];
        Entry e;
        int p;
        p = atomicAdd(&cur[dv.x >> 8], 1); e.s = sv.x; e.d = dv.x; ebuf[p] = e;
        p = atomicAdd(&cur[dv.y >> 8], 1); e.s = sv.y; e.d = dv.y; ebuf[p] = e;
        p = atomicAdd(&cur[dv.z >> 8], 1); e.s = sv.z; e.d = dv.z; ebuf[p] = e;
        p = atomicAdd(&cur[dv.w >> 8], 1); e.s = sv.w; e.d = dv.w; ebuf[p] = e;
    }
}

// ---------------- pass 4: per-bucket CSR fill + rowp + ndst ----------------
__global__ __launch_bounds__(256) void bucket_csr(const Entry* __restrict__ ebuf,
                                                  const int* __restrict__ boff,
                                                  int* __restrict__ rowp,
                                                  float* __restrict__ ndst,
                                                  int* __restrict__ csr) {
    __shared__ int hist[256];
    __shared__ int pref[256];
    __shared__ int cur[256];
    const int t = threadIdx.x, b = blockIdx.x;
    const int beg = boff[b], end = boff[b + 1];
    hist[t] = 0;
    __syncthreads();
    for (int i = beg + t; i < end; i += 256)
        atomicAdd(&hist[ebuf[i].d & 255], 1);
    __syncthreads();
    const int h = hist[t];
    pref[t] = h;
    __syncthreads();
    for (int o = 1; o < 256; o <<= 1) {
        const int v = (t >= o) ? pref[t - o] : 0;
        __syncthreads();
        pref[t] += v;
        __syncthreads();
    }
    const int val = beg + pref[t] - h;   // exclusive prefix + bucket base
    const int n = (b << 8) + t;
    if (n <= N_NODES) rowp[n] = val;
    if (n < N_NODES) ndst[n] = 1.0f / sqrtf((float)max(h, 1));
    cur[t] = val;
    __syncthreads();
    for (int i = beg + t; i < end; i += 256) {
        const Entry e = ebuf[i];
        const int pos = atomicAdd(&cur[e.d & 255], 1);
        csr[pos] = e.s;
    }
}

// ---------------- deg_out: range x chunk partial histograms ----------------
__global__ __launch_bounds__(512) void degsrc_part(const int* __restrict__ src,
                                                   int* __restrict__ partial) {
    __shared__ int h[HRS];
    const int t = threadIdx.x;
    const int r = blockIdx.x & (NRS - 1);
    const int c = blockIdx.x >> 3;
    const int base = r * HRS;
    for (int j = t; j < HRS; j += 512) h[j] = 0;
    __syncthreads();
    const int4* s4 = (const int4*)(src + (size_t)c * CS_E);
    for (int i = t; i < CS_E / 4; i += 512) {
        const int4 v = s4[i];
        unsigned u;
        u = (unsigned)(v.x - base); if (u < HRS) atomicAdd(&h[u], 1);
        u = (unsigned)(v.y - base); if (u < HRS) atomicAdd(&h[u], 1);
        u = (unsigned)(v.z - base); if (u < HRS) atomicAdd(&h[u], 1);
        u = (unsigned)(v.w - base); if (u < HRS) atomicAdd(&h[u], 1);
    }
    __syncthreads();
    for (int j = t; j < HRS; j += 512) partial[(size_t)c * (NRS * HRS) + base + j] = h[j];
}

__global__ __launch_bounds__(256) void nsrc_reduce(const int* __restrict__ partial,
                                                   float* __restrict__ nsrc) {
    const int n = blockIdx.x * 256 + threadIdx.x;
    int s = 0;
#pragma unroll
    for (int c = 0; c < NCS; ++c) s += partial[(size_t)c * (NRS * HRS) + n];
    if (n < N_NODES) nsrc[n] = 1.0f / sqrtf((float)max(s, 1));
}

// ---------------- prep: W1^T fp16 [256][512] + W2^T fp16 [48][256] (zero-pad) --
__global__ __launch_bounds__(256) void prep_w(const float* __restrict__ W1,
                                              const float* __restrict__ W2,
                                              unsigned short* __restrict__ w1t,
                                              unsigned short* __restrict__ w2t) {
    int idx = blockIdx.x * 256 + threadIdx.x;
    if (idx < IN_SIZE * HID_SIZE) {
        int n = idx >> 9;
        int k = idx & 511;
        _Float16 h = (_Float16)W1[(size_t)k * HID_SIZE + n];
        w1t[idx] = *(unsigned short*)&h;
    } else if (idx < IN_SIZE * HID_SIZE + 48 * HID_SIZE) {
        int i2 = idx - IN_SIZE * HID_SIZE;
        int o = i2 >> 8;        // 0..47
        int c = i2 & 255;       // 0..255
        float v = (o < OUT_SIZE) ? W2[(size_t)c * OUT_SIZE + o] : 0.f;
        _Float16 h = (_Float16)v;
        w2t[i2] = *(unsigned short*)&h;
    }
}

// ---------------- fused MLP: h0a = a*(relu(X@W1+b1)@W2+b2), g0 = nsrc*(...) ----
// Phase 1: BM=128, BN=256, BK=64, 8 waves, pipelined staging (regs->LDS).
// Phase 2: h1 tile through LDS in 4 wc-rounds, MFMA vs W2^T fp16, K=64/round.
// LDS union: phase1 sA[128*64]+sB[256*64] (48KB) / phase2 chunk[128*72]+w2[48*264] (43.8KB)
__global__ __launch_bounds__(512) void gemm_fused(const float* __restrict__ X,
                                                  const unsigned short* __restrict__ w1t,
                                                  const float* __restrict__ b1,
                                                  const unsigned short* __restrict__ w2t,
                                                  const float* __restrict__ b2,
                                                  const float* __restrict__ nsrc,
                                                  _Float16* __restrict__ h0a,
                                                  _Float16* __restrict__ g0) {
    __shared__ __align__(16) unsigned char lds[49152];
    _Float16* sA = (_Float16*)lds;            // [128][64]
    _Float16* sB = sA + 128 * 64;             // [256][64]
    _Float16* sC = (_Float16*)lds;            // [128][72]  (phase 2)
    _Float16* sW = sC + 128 * 72;             // [48][264]  (phase 2)

    const int t    = threadIdx.x;
    const int lane = t & 63;
    const int w    = t >> 6;        // 0..7
    const int wr   = w >> 2;        // 0..1
    const int wc   = w & 3;         // 0..3
    const int n0   = blockIdx.x * 128;

    f32x4 acc[4][4];
#pragma unroll
    for (int i = 0; i < 4; ++i)
#pragma unroll
        for (int j = 0; j < 4; ++j) acc[i][j] = (f32x4)0.f;

    const int lo = lane & 15;
    const int hi = lane >> 4;
    const int l7 = lane & 7;

    // ---- staging maps (precomputed) ----
    int rowA[2], offA[2]; bool okA[2]; const float* pA[2];
#pragma unroll
    for (int i = 0; i < 2; ++i) {
        const int id  = t + i * 512;
        const int row = id >> 3;
        const int ch  = id & 7;
        rowA[i] = row;
        offA[i] = row * 64 + ((ch ^ (row & 7)) << 3);
        const int gr = n0 + row;
        okA[i] = (gr < N_NODES);
        pA[i] = X + (size_t)(okA[i] ? gr : 0) * IN_SIZE + ch * 8;
    }
    int offB[4]; const unsigned short* pB[4];
#pragma unroll
    for (int i = 0; i < 4; ++i) {
        const int id = t + i * 512;
        const int n  = id >> 3;
        const int ch = id & 7;
        offB[i] = n * 64 + ((ch ^ (n & 7)) << 3);
        pB[i] = w1t + (size_t)n * IN_SIZE + ch * 8;
    }

    float4 xr[2][2];
#pragma unroll
    for (int i = 0; i < 2; ++i) { xr[i][0] = make_float4(0,0,0,0); xr[i][1] = xr[i][0]; }
    uint4 br[4];

    // prologue: issue loads for kk=0
#pragma unroll
    for (int i = 0; i < 2; ++i)
        if (okA[i]) { xr[i][0] = ((const float4*)pA[i])[0]; xr[i][1] = ((const float4*)pA[i])[1]; }
#pragma unroll
    for (int i = 0; i < 4; ++i) br[i] = *(const uint4*)pB[i];

    for (int kk = 0; kk < IN_SIZE; kk += 64) {
        __syncthreads();   // previous tile's compute done
        // ---- write staged regs -> LDS (fp32->fp16 convert for A) ----
#pragma unroll
        for (int i = 0; i < 2; ++i) {
            half8 hv;
            hv[0] = (_Float16)xr[i][0].x; hv[1] = (_Float16)xr[i][0].y;
            hv[2] = (_Float16)xr[i][0].z; hv[3] = (_Float16)xr[i][0].w;
            hv[4] = (_Float16)xr[i][1].x; hv[5] = (_Float16)xr[i][1].y;
            hv[6] = (_Float16)xr[i][1].z; hv[7] = (_Float16)xr[i][1].w;
            *(half8*)&sA[offA[i]] = hv;
        }
#pragma unroll
        for (int i = 0; i < 4; ++i) *(uint4*)&sB[offB[i]] = br[i];
        // ---- issue next tile's loads (in flight across barrier + MFMA) ----
        if (kk + 64 < IN_SIZE) {
#pragma unroll
            for (int i = 0; i < 2; ++i)
                if (okA[i]) {
                    xr[i][0] = ((const float4*)(pA[i] + kk + 64))[0];
                    xr[i][1] = ((const float4*)(pA[i] + kk + 64))[1];
                }
#pragma unroll
            for (int i = 0; i < 4; ++i) br[i] = *(const uint4*)(pB[i] + kk + 64);
        }
        __syncthreads();
        // ---- compute: 2 k-slices of 32 ----
#pragma unroll
        for (int s = 0; s < 2; ++s) {
            const int chs = ((s * 4 + hi) ^ l7) << 3;
            half8 af[4], bf[4];
#pragma unroll
            for (int f = 0; f < 4; ++f)
                af[f] = *(const half8*)&sA[(wr * 64 + f * 16 + lo) * 64 + chs];
#pragma unroll
            for (int f = 0; f < 4; ++f)
                bf[f] = *(const half8*)&sB[(wc * 64 + f * 16 + lo) * 64 + chs];
#pragma unroll
            for (int fi = 0; fi < 4; ++fi)
#pragma unroll
                for (int fj = 0; fj < 4; ++fj)
                    acc[fi][fj] = __builtin_amdgcn_mfma_f32_16x16x32_f16(
                        af[fi], bf[fj], acc[fi][fj], 0, 0, 0);
        }
    }

    // ---------------- phase 2: (relu(h1)) @ W2 ----------------
    float b1v[4];
#pragma unroll
    for (int fj = 0; fj < 4; ++fj) b1v[fj] = b1[wc * 64 + fj * 16 + lo];

    __syncthreads();   // phase-1 LDS reads done everywhere
    // stage W2^T: 48*256 halves = 1536 uint4
#pragma unroll
    for (int i = 0; i < 3; ++i) {
        const int id = t + i * 512;      // 0..1535
        const int o  = id >> 5;          // 0..47
        const int ch = id & 31;
        const uint4 v = *(const uint4*)(w2t + (size_t)o * HID_SIZE + ch * 8);
        *(uint4*)&sW[o * 264 + ch * 8] = v;
    }

    f32x4 acc2[3];
#pragma unroll
    for (int f = 0; f < 3; ++f) acc2[f] = (f32x4)0.f;
    float b2v[3];
#pragma unroll
    for (int f = 0; f < 3; ++f) {
        const int o = f * 16 + lo;
        b2v[f] = (o < OUT_SIZE) ? b2[o] : 0.f;
    }

    for (int j = 0; j < 4; ++j) {
        if (j) __syncthreads();          // prev round's reads done before overwrite
        if (wc == j) {
            // write this wave's h1 quarter (+b1, relu, fp16) into chunk
#pragma unroll
            for (int fi = 0; fi < 4; ++fi)
#pragma unroll
                for (int fj = 0; fj < 4; ++fj)
#pragma unroll
                    for (int r = 0; r < 4; ++r) {
                        const int rl = wr * 64 + fi * 16 + hi * 4 + r;
                        const int cl = fj * 16 + lo;
                        const float v = fmaxf(acc[fi][fj][r] + b1v[fj], 0.f);
                        sC[rl * 72 + cl] = (_Float16)v;
                    }
        }
        __syncthreads();
        // all 8 waves: wave w owns rows [w*16, w*16+16), 3 col-frags, K=64
#pragma unroll
        for (int ks = 0; ks < 2; ++ks) {
            const half8 a = *(const half8*)&sC[(w * 16 + lo) * 72 + ks * 32 + hi * 8];
#pragma unroll
            for (int f = 0; f < 3; ++f) {
                const half8 b = *(const half8*)&sW[(f * 16 + lo) * 264 + j * 64 + ks * 32 + hi * 8];
                acc2[f] = __builtin_amdgcn_mfma_f32_16x16x32_f16(a, b, acc2[f], 0, 0, 0);
            }
        }
    }

    // ---- epilogue: h0 = acc2 + b2;  h0a = ALPHA*h0 (fp16);  g0 = nsrc*h0 (fp16)
#pragma unroll
    for (int f = 0; f < 3; ++f) {
        const int o = f * 16 + lo;
#pragma unroll
        for (int r = 0; r < 4; ++r) {
            const int grow = n0 + w * 16 + hi * 4 + r;
            if (grow < N_NODES && o < OUT_SIZE) {
                const float v = acc2[f][r] + b2v[f];
                const float ns = nsrc[grow];
                g0 [(size_t)grow * 64 + o] = (_Float16)(ns * v);
                h0a[(size_t)grow * 64 + o] = (_Float16)(ALPHA * v);
            }
        }
    }
}

// ---------------- APPNP step: scaled fp16 state, unweighted gather ----------
__global__ __launch_bounds__(320) void appnp_step4(const _Float16* __restrict__ gin,
                                                   const _Float16* __restrict__ h0a,
                                                   const int* __restrict__ rowp,
                                                   const int* __restrict__ csr,
                                                   const float* __restrict__ nsrc,
                                                   const float* __restrict__ ndst,
                                                   _Float16* __restrict__ gout,
                                                   float* __restrict__ hout,
                                                   int last) {
    const int tid = threadIdx.x;
    const int ln  = tid / 5;
    const int q   = tid - ln * 5;
    const int n   = blockIdx.x * 64 + ln;
    if (n >= N_NODES) return;

    const int beg = rowp[n];
    const int end = rowp[n + 1];
    const _Float16* gq = gin + q * 8;

    float acc[8];
#pragma unroll
    for (int j = 0; j < 8; ++j) acc[j] = 0.f;

    int e = beg;
    for (; e + 4 <= end; e += 4) {
        const int s0 = csr[e + 0];
        const int s1 = csr[e + 1];
        const int s2 = csr[e + 2];
        const int s3 = csr[e + 3];
        const half8 v0 = *(const half8*)(gq + (size_t)s0 * 64);
        const half8 v1 = *(const half8*)(gq + (size_t)s1 * 64);
        const half8 v2 = *(const half8*)(gq + (size_t)s2 * 64);
        const half8 v3 = *(const half8*)(gq + (size_t)s3 * 64);
#pragma unroll
        for (int j = 0; j < 8; ++j)
            acc[j] += (float)v0[j] + (float)v1[j] + (float)v2[j] + (float)v3[j];
    }
    for (; e < end; ++e) {
        const int s0 = csr[e];
        const half8 v0 = *(const half8*)(gq + (size_t)s0 * 64);
#pragma unroll
        for (int j = 0; j < 8; ++j) acc[j] += (float)v0[j];
    }

    const float nd = (1.0f - ALPHA) * ndst[n];
    const half8 ha = *(const half8*)(h0a + (size_t)n * 64 + q * 8);
    float r[8];
#pragma unroll
    for (int j = 0; j < 8; ++j) r[j] = nd * acc[j] + (float)ha[j];

    if (last) {
        f32x4 ra, rb;
        ra[0] = r[0]; ra[1] = r[1]; ra[2] = r[2]; ra[3] = r[3];
        rb[0] = r[4]; rb[1] = r[5]; rb[2] = r[6]; rb[3] = r[7];
        *(f32x4*)(hout + (size_t)n * OUT_SIZE + q * 8) = ra;
        *(f32x4*)(hout + (size_t)n * OUT_SIZE + q * 8 + 4) = rb;
    } else {
        const float ns = nsrc[n];
        half8 gv;
#pragma unroll
        for (int j = 0; j < 8; ++j) gv[j] = (_Float16)(ns * r[j]);
        *(half8*)(gout + (size_t)n * 64 + q * 8) = gv;
    }
}

// ---------------- launcher ----------------
extern "C" void kernel_launch(void* const* d_in, const int* in_sizes, int n_in,
                              void* d_out, int out_size, void* d_ws, size_t ws_size,
                              hipStream_t stream) {
    const float* X   = (const float*)d_in[0];
    const int*   src = (const int*)d_in[1];
    const int*   dst = (const int*)d_in[2];
    const float* W1  = (const float*)d_in[3];
    const float* b1  = (const float*)d_in[4];
    const float* W2  = (const float*)d_in[5];
    const float* b2  = (const float*)d_in[6];
    float* out = (float*)d_out;

    char* ws = (char*)d_ws;
    size_t off = 0;
    auto alloc = [&](size_t bytes) -> void* {
        void* p = ws + off;
        off = (off + bytes + 255) & ~(size_t)255;
        return p;
    };
    _Float16* h0a = (_Float16*)alloc((size_t)N_NODES * 64 * 2);  // 12.8 MB
    _Float16* gA  = (_Float16*)alloc((size_t)N_NODES * 64 * 2);  // 12.8 MB
    _Float16* gB  = (_Float16*)alloc((size_t)N_NODES * 64 * 2);  // 12.8 MB
    // ebuf (12.8 MB) aliases gA: dead after bucket_csr, before gemm writes gA
    Entry* ebuf    = (Entry*)gA;
    // partial (6.5 MB) aliases gB: dead after nsrc_reduce, before step 0 writes gB
    int*   partial = (int*)gB;
    float* nsrc = (float*)alloc((size_t)N_NODES * 4);
    float* ndst = (float*)alloc((size_t)N_NODES * 4);
    int* rowp   = (int*)alloc((size_t)(N_NODES + 2) * 4);
    int* csr    = (int*)alloc((size_t)N_EDGES * 4);              // 6.4 MB
    int* cnt    = (int*)alloc((size_t)NCH * NBUK * 4);
    int* offb   = (int*)alloc((size_t)NCH * NBUK * 4);
    int* boff   = (int*)alloc((size_t)(NBUK + 1) * 4);
    unsigned short* w1t = (unsigned short*)alloc((size_t)IN_SIZE * HID_SIZE * 2);
    unsigned short* w2t = (unsigned short*)alloc((size_t)48 * HID_SIZE * 2);

    const int pgrid = (N_NODES + 63) / 64;             // 1563 (320-thread blocks)

    // ---- build first (nsrc needed by gemm epilogue) ----
    hist_pass<<<NCH, 512, 0, stream>>>(dst, cnt);
    bucket_scan<<<1, 512, 0, stream>>>(cnt, offb, boff);
    scatter_pass<<<NCH, 512, 0, stream>>>(src, dst, offb, ebuf);
    bucket_csr<<<NBUK, 256, 0, stream>>>(ebuf, boff, rowp, ndst, csr);
    degsrc_part<<<NRS * NCS, 512, 0, stream>>>(src, partial);
    nsrc_reduce<<<(NRS * HRS) / 256, 256, 0, stream>>>(partial, nsrc);

    // ---- fused MLP (writes h0a + g0 directly; ebuf/partial dead) ----
    prep_w<<<(IN_SIZE * HID_SIZE + 48 * HID_SIZE + 255) / 256, 256, 0, stream>>>(W1, W2, w1t, w2t);
    gemm_fused<<<(N_NODES + 127) / 128, 512, 0, stream>>>(X, w1t, b1, w2t, b2, nsrc, h0a, gA);

    // ---- propagation ----
    const _Float16* gin = gA;
    for (int s = 0; s < K_STEPS; ++s) {
        const int last = (s == K_STEPS - 1) ? 1 : 0;
        _Float16* gout = (s & 1) ? gA : gB;
        appnp_step4<<<pgrid, 320, 0, stream>>>(gin, h0a, rowp, csr, nsrc, ndst,
                                               gout, out, last);
        gin = gout;
    }
}